// Round 6
// baseline (257.191 us; speedup 1.0000x reference)
//
#include <hip/hip_runtime.h>
#include <hip/hip_bf16.h>
#include <math.h>

// COLoRALinear: B=4, S=2048, D_IN=D_OUT=2048, E=8, R=8, SCALING=2.0
#define BATCH 4
#define SEQ   2048
#define DIN   2048
#define DOUT  2048
#define NEXP  8
#define RANK  8
#define MTOT  (BATCH * SEQ)   // 8192
#define KE    64              // expert aug rank (shared LoRA folded into Wb)
#define KAB   96              // Ab rows: 64 expert + 8 task_emb + 24 zero pad

typedef __bf16 bf16x8 __attribute__((ext_vector_type(8)));
typedef __bf16 bf16x4 __attribute__((ext_vector_type(4)));
typedef float  f32x4  __attribute__((ext_vector_type(4)));

#define GLOBAL_AS __attribute__((address_space(1)))
#define LDS_AS    __attribute__((address_space(3)))

// ---------------------------------------------------------------------------
// K1: fused prep (6368 blocks), all vectorized:
//  [0,2048):    x -> xb bf16 (32 elems/thread, bf16x8 stores)
//  [2048,6144): Wb = bf16(W + cw*2*shared_B@shared_A)   (shared LoRA folded)
//  [6144,6272): caug[o][k] = (1-cw)*2*expert_B[k>>3][o][k&7]   (unscaled by routing)
//  [6272,6368): Ab[96][2048]: rows 0-63 expert_A, 64-71 task_emb, 72-95 zero
// ---------------------------------------------------------------------------
__global__ __launch_bounds__(256) void prep_all(
    const float* __restrict__ x, const float* __restrict__ W,
    const float* __restrict__ expert_A, const float* __restrict__ shared_A,
    const float* __restrict__ expert_B, const float* __restrict__ shared_B,
    const float* __restrict__ task_emb, const float* __restrict__ collab,
    __bf16* __restrict__ xb, __bf16* __restrict__ Wb,
    __bf16* __restrict__ caug, __bf16* __restrict__ Ab)
{
    const int bid = blockIdx.x;
    const int t = threadIdx.x;
    if (bid < 2048) {
        size_t base = (size_t)bid * 8192 + (size_t)t * 32;
        #pragma unroll
        for (int j = 0; j < 4; ++j) {
            float4 v0 = *(const float4*)&x[base + j * 8];
            float4 v1 = *(const float4*)&x[base + j * 8 + 4];
            bf16x8 h = { (__bf16)v0.x, (__bf16)v0.y, (__bf16)v0.z, (__bf16)v0.w,
                         (__bf16)v1.x, (__bf16)v1.y, (__bf16)v1.z, (__bf16)v1.w };
            *(bf16x8*)&xb[base + j * 8] = h;
        }
    } else if (bid < 6144) {
        size_t idx = (size_t)(bid - 2048) * 1024 + t * 4;
        int o = (int)(idx >> 11), i = (int)(idx & 2047);
        float cw = 1.0f / (1.0f + expf(-collab[0]));
        float s = cw * 2.0f;
        float4 w = *(const float4*)&W[idx];
        float dx = 0.f, dy = 0.f, dz = 0.f, dw = 0.f;
        #pragma unroll
        for (int r = 0; r < 8; ++r) {
            float bs = shared_B[(size_t)o * RANK + r];
            float4 as = *(const float4*)&shared_A[(size_t)r * DIN + i];
            dx += bs * as.x; dy += bs * as.y; dz += bs * as.z; dw += bs * as.w;
        }
        bf16x4 h = { (__bf16)(w.x + s * dx), (__bf16)(w.y + s * dy),
                     (__bf16)(w.z + s * dz), (__bf16)(w.w + s * dw) };
        *(bf16x4*)&Wb[idx] = h;
    } else if (bid < 6272) {
        int idx = (bid - 6144) * 1024 + t * 4;   // over 2048*64
        int o = idx >> 6, k = idx & 63;          // k multiple of 4
        float cw = 1.0f / (1.0f + expf(-collab[0]));
        float s = (1.0f - cw) * 2.0f;
        float4 v = *(const float4*)&expert_B[((size_t)(k >> 3) * DOUT + o) * RANK + (k & 7)];
        bf16x4 h = { (__bf16)(s * v.x), (__bf16)(s * v.y),
                     (__bf16)(s * v.z), (__bf16)(s * v.w) };
        *(bf16x4*)&caug[idx] = h;
    } else {
        int row = bid - 6272;                    // 0..95, one row per block
        int c = t * 8;
        bf16x8 h = { (__bf16)0.f, (__bf16)0.f, (__bf16)0.f, (__bf16)0.f,
                     (__bf16)0.f, (__bf16)0.f, (__bf16)0.f, (__bf16)0.f };
        if (row < 64) {
            float4 v0 = *(const float4*)&expert_A[(size_t)row * DIN + c];
            float4 v1 = *(const float4*)&expert_A[(size_t)row * DIN + c + 4];
            h = bf16x8{ (__bf16)v0.x, (__bf16)v0.y, (__bf16)v0.z, (__bf16)v0.w,
                        (__bf16)v1.x, (__bf16)v1.y, (__bf16)v1.z, (__bf16)v1.w };
        } else if (row < 72) {
            float4 v0 = *(const float4*)&task_emb[(size_t)(row - 64) * DIN + c];
            float4 v1 = *(const float4*)&task_emb[(size_t)(row - 64) * DIN + c + 4];
            h = bf16x8{ (__bf16)v0.x, (__bf16)v0.y, (__bf16)v0.z, (__bf16)v0.w,
                        (__bf16)v1.x, (__bf16)v1.y, (__bf16)v1.z, (__bf16)v1.w };
        }
        *(bf16x8*)&Ab[(size_t)row * DIN + c] = h;
    }
}

// ---------------------------------------------------------------------------
// K2 (256 blocks): split-K-4 low-rank GEMM, BK=64, 8-slot XOR swizzle.
// Block (kc = bid&3, m-tile = bid>>2): t-chunk[128 rows][80 cols] where
// cols 0-63 = expert dims -> pt[kc][m][64] bf16; cols 64-71 = x.task_emb
// partial dots -> block-reduced, atomicAdd into logits[b][8] (zeroed upstream).
// ---------------------------------------------------------------------------
__global__ __launch_bounds__(256) void gemm_t(
    const __bf16* __restrict__ xb, const __bf16* __restrict__ Ab,
    __bf16* __restrict__ pt, float* __restrict__ logits)
{
    __shared__ __bf16 lsA[128 * 64];
    __shared__ __bf16 lsB[KAB * 64];
    __shared__ float lsc[32];
    const int bid = blockIdx.x;
    const int t = threadIdx.x;
    const int lane = t & 63;
    const int w = t >> 6;                 // wave: rows w*32 .. w*32+31
    const int kc = bid & 3;
    const int m0 = (bid >> 2) * 128;
    const int b  = bid >> 6;

    f32x4 acc[2][5];
    #pragma unroll
    for (int a = 0; a < 2; ++a)
        #pragma unroll
        for (int c = 0; c < 5; ++c) acc[a][c] = (f32x4){0.f, 0.f, 0.f, 0.f};

    for (int k0 = kc * 512; k0 < kc * 512 + 512; k0 += 64) {
        #pragma unroll
        for (int q = 0; q < 4; ++q) {          // A: 128 rows x 8 slots
            int G = q * 256 + t;
            int row = G >> 3, sl = G & 7, seg = sl ^ (row & 7);
            const __bf16* gp = xb + (size_t)(m0 + row) * DIN + k0 + seg * 8;
            __builtin_amdgcn_global_load_lds((GLOBAL_AS void*)gp,
                (LDS_AS void*)&lsA[(q * 256 + (t & ~63)) * 8], 16, 0, 0);
        }
        #pragma unroll
        for (int q = 0; q < 3; ++q) {          // B: 96 rows x 8 slots
            int G = q * 256 + t;
            int row = G >> 3, sl = G & 7, seg = sl ^ (row & 7);
            const __bf16* gp = Ab + (size_t)row * DIN + k0 + seg * 8;
            __builtin_amdgcn_global_load_lds((GLOBAL_AS void*)gp,
                (LDS_AS void*)&lsB[(q * 256 + (t & ~63)) * 8], 16, 0, 0);
        }
        __syncthreads();
        #pragma unroll
        for (int kk = 0; kk < 2; ++kk) {
            bf16x8 af[2], bfr[5];
            #pragma unroll
            for (int tm = 0; tm < 2; ++tm) {
                int r = w * 32 + tm * 16 + (lane & 15);
                int slot = (kk * 4 + (lane >> 4)) ^ (r & 7);
                af[tm] = *(const bf16x8*)&lsA[r * 64 + slot * 8];
            }
            #pragma unroll
            for (int tn = 0; tn < 5; ++tn) {
                int r = tn * 16 + (lane & 15);
                int slot = (kk * 4 + (lane >> 4)) ^ (r & 7);
                bfr[tn] = *(const bf16x8*)&lsB[r * 64 + slot * 8];
            }
            #pragma unroll
            for (int tm = 0; tm < 2; ++tm)
                #pragma unroll
                for (int tn = 0; tn < 5; ++tn)
                    acc[tm][tn] = __builtin_amdgcn_mfma_f32_16x16x32_bf16(
                        af[tm], bfr[tn], acc[tm][tn], 0, 0, 0);
        }
        __syncthreads();
    }

    // pt stores (cols 0-63)
    #pragma unroll
    for (int tm = 0; tm < 2; ++tm)
        #pragma unroll
        for (int tn = 0; tn < 4; ++tn) {
            int col = tn * 16 + (lane & 15);
            #pragma unroll
            for (int v = 0; v < 4; ++v) {
                int row = m0 + w * 32 + tm * 16 + (lane >> 4) * 4 + v;
                pt[((size_t)kc * MTOT + row) * KE + col] = (__bf16)acc[tm][tn][v];
            }
        }

    // logit reduction (cols 64-71 = frag tn=4, lanes with (lane&15)<8)
    float s = 0.f;
    #pragma unroll
    for (int tm = 0; tm < 2; ++tm)
        #pragma unroll
        for (int v = 0; v < 4; ++v) s += acc[tm][4][v];
    s += __shfl_down(s, 32);
    s += __shfl_down(s, 16);   // lanes 0-15 hold column totals over wave's 32 rows
    if (lane < 8) lsc[w * 8 + lane] = s;
    __syncthreads();
    if (t < 8) {
        float tot = lsc[t] + lsc[8 + t] + lsc[16 + t] + lsc[24 + t];
        atomicAdd(&logits[b * NEXP + t], tot);
    }
}

// ---------------------------------------------------------------------------
// K3: out = xb @ Wb^T + (routing-scaled t) @ caug^T + bias
// Prologue: softmax(logits/SEQ) -> f[8].
// Correction first: caug staged (swizzled global_load_lds); A-frags built in
// VGPR from the 4 pt chunks (fp32 sum, scale by f, round bf16); 1 BK=64 kstep.
// Then 32 main BK=64 ksteps (hoisted addressing). grid (x=64 m, y=16 n) for
// XCD locality on the shared A-tile.
// ---------------------------------------------------------------------------
__global__ __launch_bounds__(256) void gemm_main(
    const __bf16* __restrict__ xb, const __bf16* __restrict__ Wb,
    const __bf16* __restrict__ pt, const __bf16* __restrict__ caug,
    const float* __restrict__ logits, const float* __restrict__ bias,
    float* __restrict__ out)
{
    __shared__ __bf16 lsA[128 * 64];
    __shared__ __bf16 lsB[128 * 64];
    const int t = threadIdx.x;
    const int lane = t & 63;
    const int wm = (t >> 6) >> 1, wn = (t >> 6) & 1;
    const int m0 = blockIdx.x * 128;
    const int n0 = blockIdx.y * 128;
    const int b  = m0 >> 11;

    // softmax -> routing factors
    float f[NEXP];
    {
        float li[NEXP];
        #pragma unroll
        for (int e = 0; e < NEXP; ++e) li[e] = logits[b * NEXP + e] * (1.0f / (float)SEQ);
        float mx = li[0];
        #pragma unroll
        for (int e = 1; e < NEXP; ++e) mx = fmaxf(mx, li[e]);
        float den = 0.f;
        #pragma unroll
        for (int e = 0; e < NEXP; ++e) { f[e] = expf(li[e] - mx); den += f[e]; }
        float rden = 1.0f / den;
        #pragma unroll
        for (int e = 0; e < NEXP; ++e) f[e] *= rden;
    }

    int rowq[4], segq[4], ldso[4];
    #pragma unroll
    for (int q = 0; q < 4; ++q) {
        rowq[q] = q * 32 + (t >> 3);
        segq[q] = (t & 7) ^ (rowq[q] & 7);
        ldso[q] = (q * 256 + (t & ~63)) * 8;
    }
    int aoff[2][4], boff[2][4];
    #pragma unroll
    for (int tm = 0; tm < 4; ++tm) {
        int r = wm * 64 + tm * 16 + (lane & 15);
        #pragma unroll
        for (int kk = 0; kk < 2; ++kk)
            aoff[kk][tm] = r * 64 + (((kk * 4 + (lane >> 4)) ^ (r & 7)) * 8);
    }
    #pragma unroll
    for (int tn = 0; tn < 4; ++tn) {
        int r = wn * 64 + tn * 16 + (lane & 15);
        #pragma unroll
        for (int kk = 0; kk < 2; ++kk)
            boff[kk][tn] = r * 64 + (((kk * 4 + (lane >> 4)) ^ (r & 7)) * 8);
    }

    f32x4 acc[4][4];
    #pragma unroll
    for (int a = 0; a < 4; ++a)
        #pragma unroll
        for (int c = 0; c < 4; ++c) acc[a][c] = (f32x4){0.f, 0.f, 0.f, 0.f};

    // ---- correction kstep: acc += t_scaled @ caug^T  (K=64) ----
    {
        #pragma unroll
        for (int q = 0; q < 4; ++q) {
            const __bf16* gp = caug + (size_t)(n0 + rowq[q]) * KE + segq[q] * 8;
            __builtin_amdgcn_global_load_lds((GLOBAL_AS void*)gp,
                (LDS_AS void*)&lsB[ldso[q]], 16, 0, 0);
        }
        __syncthreads();
        #pragma unroll
        for (int kk = 0; kk < 2; ++kk) {
            float fe = f[kk * 4 + (lane >> 4)];
            bf16x8 afc[4], bfr[4];
            #pragma unroll
            for (int tm = 0; tm < 4; ++tm) {
                int rm = m0 + wm * 64 + tm * 16 + (lane & 15);
                int kb = kk * 32 + (lane >> 4) * 8;
                const __bf16* p0 = pt + (size_t)rm * KE + kb;
                bf16x8 v0 = *(const bf16x8*)(p0);
                bf16x8 v1 = *(const bf16x8*)(p0 + (size_t)MTOT * KE);
                bf16x8 v2 = *(const bf16x8*)(p0 + (size_t)2 * MTOT * KE);
                bf16x8 v3 = *(const bf16x8*)(p0 + (size_t)3 * MTOT * KE);
                bf16x8 r;
                #pragma unroll
                for (int j = 0; j < 8; ++j)
                    r[j] = (__bf16)(((float)v0[j] + (float)v1[j] +
                                     (float)v2[j] + (float)v3[j]) * fe);
                afc[tm] = r;
            }
            #pragma unroll
            for (int tn = 0; tn < 4; ++tn) bfr[tn] = *(const bf16x8*)&lsB[boff[kk][tn]];
            #pragma unroll
            for (int tm = 0; tm < 4; ++tm)
                #pragma unroll
                for (int tn = 0; tn < 4; ++tn)
                    acc[tm][tn] = __builtin_amdgcn_mfma_f32_16x16x32_bf16(
                        afc[tm], bfr[tn], acc[tm][tn], 0, 0, 0);
        }
        __syncthreads();
    }

    // ---- main: K = 2048 over (xb, Wb), 32 iters of BK=64 ----
    const __bf16* pA[4]; const __bf16* pB[4];
    #pragma unroll
    for (int q = 0; q < 4; ++q) {
        pA[q] = xb + (size_t)(m0 + rowq[q]) * DIN + segq[q] * 8;
        pB[q] = Wb + (size_t)(n0 + rowq[q]) * DIN + segq[q] * 8;
    }
    for (int it = 0; it < 32; ++it) {
        #pragma unroll
        for (int q = 0; q < 4; ++q) {
            __builtin_amdgcn_global_load_lds((GLOBAL_AS void*)pA[q],
                (LDS_AS void*)&lsA[ldso[q]], 16, 0, 0);
            __builtin_amdgcn_global_load_lds((GLOBAL_AS void*)pB[q],
                (LDS_AS void*)&lsB[ldso[q]], 16, 0, 0);
            pA[q] += 64; pB[q] += 64;
        }
        __syncthreads();
        #pragma unroll
        for (int kk = 0; kk < 2; ++kk) {
            bf16x8 af[4], bfr[4];
            #pragma unroll
            for (int tm = 0; tm < 4; ++tm) af[tm]  = *(const bf16x8*)&lsA[aoff[kk][tm]];
            #pragma unroll
            for (int tn = 0; tn < 4; ++tn) bfr[tn] = *(const bf16x8*)&lsB[boff[kk][tn]];
            #pragma unroll
            for (int tm = 0; tm < 4; ++tm)
                #pragma unroll
                for (int tn = 0; tn < 4; ++tn)
                    acc[tm][tn] = __builtin_amdgcn_mfma_f32_16x16x32_bf16(
                        af[tm], bfr[tn], acc[tm][tn], 0, 0, 0);
        }
        __syncthreads();
    }

    #pragma unroll
    for (int tm = 0; tm < 4; ++tm)
        #pragma unroll
        for (int tn = 0; tn < 4; ++tn) {
            int col = n0 + wn * 64 + tn * 16 + (lane & 15);
            float bv = bias[col];
            #pragma unroll
            for (int v = 0; v < 4; ++v) {
                int row = m0 + wm * 64 + tm * 16 + (lane >> 4) * 4 + v;
                out[(size_t)row * DOUT + col] = acc[tm][tn][v] + bv;
            }
        }
}

// ---------------------------------------------------------------------------
// Workspace (bytes):
//   xb      @ 0         : 33,554,432   (8192x2048 bf16)
//   Wb      @ 33554432  :  8,388,608   (2048x2048 bf16, shared LoRA folded)
//   pt      @ 41943040  :  4,194,304   (4x8192x64 bf16)
//   caug    @ 46137344  :    262,144   (2048x64 bf16)
//   Ab      @ 46399488  :    393,216   (96x2048 bf16)
//   logits  @ 46792704  :        256   (4x8 f32, zeroed each launch)
// ---------------------------------------------------------------------------
extern "C" void kernel_launch(void* const* d_in, const int* in_sizes, int n_in,
                              void* d_out, int out_size, void* d_ws, size_t ws_size,
                              hipStream_t stream)
{
    const float* x        = (const float*)d_in[0];
    const float* base_W   = (const float*)d_in[1];
    const float* base_b   = (const float*)d_in[2];
    const float* shared_A = (const float*)d_in[3];
    const float* shared_B = (const float*)d_in[4];
    const float* expert_A = (const float*)d_in[5];
    const float* expert_B = (const float*)d_in[6];
    const float* task_emb = (const float*)d_in[7];
    const float* collab_w = (const float*)d_in[8];
    float* out = (float*)d_out;

    char* ws = (char*)d_ws;
    __bf16* xb     = (__bf16*)(ws + 0);
    __bf16* Wb     = (__bf16*)(ws + 33554432);
    __bf16* pt     = (__bf16*)(ws + 41943040);
    __bf16* caug   = (__bf16*)(ws + 46137344);
    __bf16* Ab     = (__bf16*)(ws + 46399488);
    float*  logits = (float*) (ws + 46792704);

    hipMemsetAsync(logits, 0, 256, stream);
    prep_all <<<dim3(6368), 256, 0, stream>>>(x, base_W, expert_A, shared_A,
                                              expert_B, shared_B, task_emb, collab_w,
                                              xb, Wb, caug, Ab);
    gemm_t   <<<dim3(256), 256, 0, stream>>>(xb, Ab, pt, logits);
    gemm_main<<<dim3(64, 16), 256, 0, stream>>>(xb, Wb, pt, caug, logits, base_b, out);
}

// Round 7
// 235.379 us; speedup vs baseline: 1.0927x; 1.0927x over previous
//
#include <hip/hip_runtime.h>
#include <hip/hip_bf16.h>
#include <math.h>

// COLoRALinear: B=4, S=2048, D_IN=D_OUT=2048, E=8, R=8, SCALING=2.0
#define BATCH 4
#define SEQ   2048
#define DIN   2048
#define DOUT  2048
#define NEXP  8
#define RANK  8
#define MTOT  (BATCH * SEQ)   // 8192
#define KE    64              // expert aug rank (shared LoRA folded into Wb)
#define KAB   96              // Ab rows: 64 expert + 8 task_emb + 24 zero pad

typedef __bf16 bf16x8 __attribute__((ext_vector_type(8)));
typedef __bf16 bf16x4 __attribute__((ext_vector_type(4)));
typedef float  f32x4  __attribute__((ext_vector_type(4)));

#define GLOBAL_AS __attribute__((address_space(1)))
#define LDS_AS    __attribute__((address_space(3)))

// ---------------------------------------------------------------------------
// K1: fused prep (12512 blocks), every part lane-coalesced:
//  [0,8192):      x -> xb bf16: thread = 8 consecutive elems (2x float4 load,
//                 one bf16x8 16B store; wave covers 2KB contiguous)
//  [8192,12288):  Wb = bf16(W + cw*2*shared_B@shared_A)  (4 elems/thread)
//  [12288,12416): caug[o][k] = (1-cw)*2*expert_B[k>>3][o][k&7]
//  [12416,12512): Ab[96][2048]: rows 0-63 expert_A, 64-71 task_emb, 72-95 zero
// ---------------------------------------------------------------------------
__global__ __launch_bounds__(256) void prep_all(
    const float* __restrict__ x, const float* __restrict__ W,
    const float* __restrict__ expert_A, const float* __restrict__ shared_A,
    const float* __restrict__ expert_B, const float* __restrict__ shared_B,
    const float* __restrict__ task_emb, const float* __restrict__ collab,
    __bf16* __restrict__ xb, __bf16* __restrict__ Wb,
    __bf16* __restrict__ caug, __bf16* __restrict__ Ab)
{
    const int bid = blockIdx.x;
    const int t = threadIdx.x;
    if (bid < 8192) {
        size_t base = ((size_t)bid * 256 + t) * 8;
        float4 v0 = *(const float4*)&x[base];
        float4 v1 = *(const float4*)&x[base + 4];
        bf16x8 h = { (__bf16)v0.x, (__bf16)v0.y, (__bf16)v0.z, (__bf16)v0.w,
                     (__bf16)v1.x, (__bf16)v1.y, (__bf16)v1.z, (__bf16)v1.w };
        *(bf16x8*)&xb[base] = h;
    } else if (bid < 12288) {
        size_t idx = ((size_t)(bid - 8192) * 256 + t) * 4;
        int o = (int)(idx >> 11), i = (int)(idx & 2047);
        float cw = 1.0f / (1.0f + expf(-collab[0]));
        float s = cw * 2.0f;
        float4 w = *(const float4*)&W[idx];
        float dx = 0.f, dy = 0.f, dz = 0.f, dw = 0.f;
        #pragma unroll
        for (int r = 0; r < 8; ++r) {
            float bs = shared_B[(size_t)o * RANK + r];
            float4 as = *(const float4*)&shared_A[(size_t)r * DIN + i];
            dx += bs * as.x; dy += bs * as.y; dz += bs * as.z; dw += bs * as.w;
        }
        bf16x4 h = { (__bf16)(w.x + s * dx), (__bf16)(w.y + s * dy),
                     (__bf16)(w.z + s * dz), (__bf16)(w.w + s * dw) };
        *(bf16x4*)&Wb[idx] = h;
    } else if (bid < 12416) {
        int idx = ((bid - 12288) * 256 + t) * 4;  // over 2048*64
        int o = idx >> 6, k = idx & 63;           // k multiple of 4
        float cw = 1.0f / (1.0f + expf(-collab[0]));
        float s = (1.0f - cw) * 2.0f;
        float4 v = *(const float4*)&expert_B[((size_t)(k >> 3) * DOUT + o) * RANK + (k & 7)];
        bf16x4 h = { (__bf16)(s * v.x), (__bf16)(s * v.y),
                     (__bf16)(s * v.z), (__bf16)(s * v.w) };
        *(bf16x4*)&caug[idx] = h;
    } else {
        int row = bid - 12416;                    // 0..95, one row per block
        int c = t * 8;
        bf16x8 h = { (__bf16)0.f, (__bf16)0.f, (__bf16)0.f, (__bf16)0.f,
                     (__bf16)0.f, (__bf16)0.f, (__bf16)0.f, (__bf16)0.f };
        if (row < 64) {
            float4 v0 = *(const float4*)&expert_A[(size_t)row * DIN + c];
            float4 v1 = *(const float4*)&expert_A[(size_t)row * DIN + c + 4];
            h = bf16x8{ (__bf16)v0.x, (__bf16)v0.y, (__bf16)v0.z, (__bf16)v0.w,
                        (__bf16)v1.x, (__bf16)v1.y, (__bf16)v1.z, (__bf16)v1.w };
        } else if (row < 72) {
            float4 v0 = *(const float4*)&task_emb[(size_t)(row - 64) * DIN + c];
            float4 v1 = *(const float4*)&task_emb[(size_t)(row - 64) * DIN + c + 4];
            h = bf16x8{ (__bf16)v0.x, (__bf16)v0.y, (__bf16)v0.z, (__bf16)v0.w,
                        (__bf16)v1.x, (__bf16)v1.y, (__bf16)v1.z, (__bf16)v1.w };
        }
        *(bf16x8*)&Ab[(size_t)row * DIN + c] = h;
    }
}

// ---------------------------------------------------------------------------
// K2 (256 blocks): split-K-4 low-rank GEMM, BK=64, 8-slot XOR swizzle.
// Block (kc = bid&3, m-tile = bid>>2): cols 0-63 -> pt[kc][m][64] bf16;
// cols 64-71 = x.task_emb partial dots -> block-reduce, atomicAdd logits[b][8].
// ---------------------------------------------------------------------------
__global__ __launch_bounds__(256) void gemm_t(
    const __bf16* __restrict__ xb, const __bf16* __restrict__ Ab,
    __bf16* __restrict__ pt, float* __restrict__ logits)
{
    __shared__ __bf16 lsA[128 * 64];
    __shared__ __bf16 lsB[KAB * 64];
    __shared__ float lsc[32];
    const int bid = blockIdx.x;
    const int t = threadIdx.x;
    const int lane = t & 63;
    const int w = t >> 6;                 // wave: rows w*32 .. w*32+31
    const int kc = bid & 3;
    const int m0 = (bid >> 2) * 128;
    const int b  = bid >> 6;

    f32x4 acc[2][5];
    #pragma unroll
    for (int a = 0; a < 2; ++a)
        #pragma unroll
        for (int c = 0; c < 5; ++c) acc[a][c] = (f32x4){0.f, 0.f, 0.f, 0.f};

    for (int k0 = kc * 512; k0 < kc * 512 + 512; k0 += 64) {
        #pragma unroll
        for (int q = 0; q < 4; ++q) {          // A: 128 rows x 8 slots
            int G = q * 256 + t;
            int row = G >> 3, sl = G & 7, seg = sl ^ (row & 7);
            const __bf16* gp = xb + (size_t)(m0 + row) * DIN + k0 + seg * 8;
            __builtin_amdgcn_global_load_lds((GLOBAL_AS void*)gp,
                (LDS_AS void*)&lsA[(q * 256 + (t & ~63)) * 8], 16, 0, 0);
        }
        #pragma unroll
        for (int q = 0; q < 3; ++q) {          // B: 96 rows x 8 slots
            int G = q * 256 + t;
            int row = G >> 3, sl = G & 7, seg = sl ^ (row & 7);
            const __bf16* gp = Ab + (size_t)row * DIN + k0 + seg * 8;
            __builtin_amdgcn_global_load_lds((GLOBAL_AS void*)gp,
                (LDS_AS void*)&lsB[(q * 256 + (t & ~63)) * 8], 16, 0, 0);
        }
        __syncthreads();
        #pragma unroll
        for (int kk = 0; kk < 2; ++kk) {
            bf16x8 af[2], bfr[5];
            #pragma unroll
            for (int tm = 0; tm < 2; ++tm) {
                int r = w * 32 + tm * 16 + (lane & 15);
                int slot = (kk * 4 + (lane >> 4)) ^ (r & 7);
                af[tm] = *(const bf16x8*)&lsA[r * 64 + slot * 8];
            }
            #pragma unroll
            for (int tn = 0; tn < 5; ++tn) {
                int r = tn * 16 + (lane & 15);
                int slot = (kk * 4 + (lane >> 4)) ^ (r & 7);
                bfr[tn] = *(const bf16x8*)&lsB[r * 64 + slot * 8];
            }
            #pragma unroll
            for (int tm = 0; tm < 2; ++tm)
                #pragma unroll
                for (int tn = 0; tn < 5; ++tn)
                    acc[tm][tn] = __builtin_amdgcn_mfma_f32_16x16x32_bf16(
                        af[tm], bfr[tn], acc[tm][tn], 0, 0, 0);
        }
        __syncthreads();
    }

    #pragma unroll
    for (int tm = 0; tm < 2; ++tm)
        #pragma unroll
        for (int tn = 0; tn < 4; ++tn) {
            int col = tn * 16 + (lane & 15);
            #pragma unroll
            for (int v = 0; v < 4; ++v) {
                int row = m0 + w * 32 + tm * 16 + (lane >> 4) * 4 + v;
                pt[((size_t)kc * MTOT + row) * KE + col] = (__bf16)acc[tm][tn][v];
            }
        }

    float s = 0.f;
    #pragma unroll
    for (int tm = 0; tm < 2; ++tm)
        #pragma unroll
        for (int v = 0; v < 4; ++v) s += acc[tm][4][v];
    s += __shfl_down(s, 32);
    s += __shfl_down(s, 16);
    if (lane < 8) lsc[w * 8 + lane] = s;
    __syncthreads();
    if (t < 8) {
        float tot = lsc[t] + lsc[8 + t] + lsc[16 + t] + lsc[24 + t];
        atomicAdd(&logits[b * NEXP + t], tot);
    }
}

// ---------------------------------------------------------------------------
// K3: tb[m][k] = bf16( softmax(logits[b]/SEQ)[k>>3] * sum_kc pt[kc][m][k] )
// 512 blocks; softmax recomputed per-thread (8 expf, trivial).
// ---------------------------------------------------------------------------
__global__ __launch_bounds__(256) void reduce_route(
    const __bf16* __restrict__ pt, const float* __restrict__ logits,
    __bf16* __restrict__ tb)
{
    size_t idx = ((size_t)blockIdx.x * 256 + threadIdx.x) * 4;  // over 8192*64
    int k0 = (int)(idx & 63);
    int m  = (int)(idx >> 6);
    int b  = m >> 11;
    float li[NEXP];
    #pragma unroll
    for (int e = 0; e < NEXP; ++e) li[e] = logits[b * NEXP + e] * (1.0f / (float)SEQ);
    float mx = li[0];
    #pragma unroll
    for (int e = 1; e < NEXP; ++e) mx = fmaxf(mx, li[e]);
    float den = 0.f, ex[NEXP];
    #pragma unroll
    for (int e = 0; e < NEXP; ++e) { ex[e] = expf(li[e] - mx); den += ex[e]; }
    float f = ex[k0 >> 3] / den;
    float sx = 0.f, sy = 0.f, sz = 0.f, sw = 0.f;
    #pragma unroll
    for (int kc = 0; kc < 4; ++kc) {
        bf16x4 v = *(const bf16x4*)&pt[(size_t)kc * MTOT * KE + idx];
        sx += (float)v[0]; sy += (float)v[1]; sz += (float)v[2]; sw += (float)v[3];
    }
    bf16x4 h = { (__bf16)(sx * f), (__bf16)(sy * f), (__bf16)(sz * f), (__bf16)(sw * f) };
    *(bf16x4*)&tb[idx] = h;
}

// ---------------------------------------------------------------------------
// K4: out = xb @ Wb^T + tb @ caug^T + bias   (R5 structure verbatim, 85.9 us)
// BK=64, 8-slot XOR swizzle, hoisted addressing; correction = ONE kstep (KE=64).
// grid (x=64 m-tiles, y=16 n-tiles) for XCD locality on the shared A-tile.
// ---------------------------------------------------------------------------
__global__ __launch_bounds__(256) void gemm_main(
    const __bf16* __restrict__ xb, const __bf16* __restrict__ Wb,
    const __bf16* __restrict__ tb, const __bf16* __restrict__ caug,
    const float* __restrict__ bias, float* __restrict__ out)
{
    __shared__ __bf16 lsA[128 * 64];
    __shared__ __bf16 lsB[128 * 64];
    const int t = threadIdx.x;
    const int lane = t & 63;
    const int wm = (t >> 6) >> 1, wn = (t >> 6) & 1;
    const int m0 = blockIdx.x * 128;
    const int n0 = blockIdx.y * 128;

    int rowq[4], segq[4], ldso[4];
    #pragma unroll
    for (int q = 0; q < 4; ++q) {
        rowq[q] = q * 32 + (t >> 3);
        segq[q] = (t & 7) ^ (rowq[q] & 7);
        ldso[q] = (q * 256 + (t & ~63)) * 8;
    }
    const __bf16* pA[4]; const __bf16* pB[4];
    #pragma unroll
    for (int q = 0; q < 4; ++q) {
        pA[q] = xb + (size_t)(m0 + rowq[q]) * DIN + segq[q] * 8;
        pB[q] = Wb + (size_t)(n0 + rowq[q]) * DIN + segq[q] * 8;
    }
    int aoff[2][4], boff[2][4];
    #pragma unroll
    for (int tm = 0; tm < 4; ++tm) {
        int r = wm * 64 + tm * 16 + (lane & 15);
        #pragma unroll
        for (int kk = 0; kk < 2; ++kk)
            aoff[kk][tm] = r * 64 + (((kk * 4 + (lane >> 4)) ^ (r & 7)) * 8);
    }
    #pragma unroll
    for (int tn = 0; tn < 4; ++tn) {
        int r = wn * 64 + tn * 16 + (lane & 15);
        #pragma unroll
        for (int kk = 0; kk < 2; ++kk)
            boff[kk][tn] = r * 64 + (((kk * 4 + (lane >> 4)) ^ (r & 7)) * 8);
    }

    f32x4 acc[4][4];
    #pragma unroll
    for (int a = 0; a < 4; ++a)
        #pragma unroll
        for (int c = 0; c < 4; ++c) acc[a][c] = (f32x4){0.f, 0.f, 0.f, 0.f};

    for (int it = 0; it < 32; ++it) {
        #pragma unroll
        for (int q = 0; q < 4; ++q) {
            __builtin_amdgcn_global_load_lds((GLOBAL_AS void*)pA[q],
                (LDS_AS void*)&lsA[ldso[q]], 16, 0, 0);
            __builtin_amdgcn_global_load_lds((GLOBAL_AS void*)pB[q],
                (LDS_AS void*)&lsB[ldso[q]], 16, 0, 0);
            pA[q] += 64; pB[q] += 64;
        }
        __syncthreads();
        #pragma unroll
        for (int kk = 0; kk < 2; ++kk) {
            bf16x8 af[4], bfr[4];
            #pragma unroll
            for (int tm = 0; tm < 4; ++tm) af[tm]  = *(const bf16x8*)&lsA[aoff[kk][tm]];
            #pragma unroll
            for (int tn = 0; tn < 4; ++tn) bfr[tn] = *(const bf16x8*)&lsB[boff[kk][tn]];
            #pragma unroll
            for (int tm = 0; tm < 4; ++tm)
                #pragma unroll
                for (int tn = 0; tn < 4; ++tn)
                    acc[tm][tn] = __builtin_amdgcn_mfma_f32_16x16x32_bf16(
                        af[tm], bfr[tn], acc[tm][tn], 0, 0, 0);
        }
        __syncthreads();
    }

    {   // correction: single BK=64 kstep over (tb, caug), stride KE=64
        #pragma unroll
        for (int q = 0; q < 4; ++q) {
            const __bf16* qA = tb   + (size_t)(m0 + rowq[q]) * KE + segq[q] * 8;
            const __bf16* qB = caug + (size_t)(n0 + rowq[q]) * KE + segq[q] * 8;
            __builtin_amdgcn_global_load_lds((GLOBAL_AS void*)qA,
                (LDS_AS void*)&lsA[ldso[q]], 16, 0, 0);
            __builtin_amdgcn_global_load_lds((GLOBAL_AS void*)qB,
                (LDS_AS void*)&lsB[ldso[q]], 16, 0, 0);
        }
        __syncthreads();
        #pragma unroll
        for (int kk = 0; kk < 2; ++kk) {
            bf16x8 af[4], bfr[4];
            #pragma unroll
            for (int tm = 0; tm < 4; ++tm) af[tm]  = *(const bf16x8*)&lsA[aoff[kk][tm]];
            #pragma unroll
            for (int tn = 0; tn < 4; ++tn) bfr[tn] = *(const bf16x8*)&lsB[boff[kk][tn]];
            #pragma unroll
            for (int tm = 0; tm < 4; ++tm)
                #pragma unroll
                for (int tn = 0; tn < 4; ++tn)
                    acc[tm][tn] = __builtin_amdgcn_mfma_f32_16x16x32_bf16(
                        af[tm], bfr[tn], acc[tm][tn], 0, 0, 0);
        }
        __syncthreads();
    }

    #pragma unroll
    for (int tm = 0; tm < 4; ++tm)
        #pragma unroll
        for (int tn = 0; tn < 4; ++tn) {
            int col = n0 + wn * 64 + tn * 16 + (lane & 15);
            float bv = bias[col];
            #pragma unroll
            for (int v = 0; v < 4; ++v) {
                int row = m0 + wm * 64 + tm * 16 + (lane >> 4) * 4 + v;
                out[(size_t)row * DOUT + col] = acc[tm][tn][v] + bv;
            }
        }
}

// ---------------------------------------------------------------------------
// Workspace (bytes):
//   xb      @ 0         : 33,554,432   (8192x2048 bf16)
//   Wb      @ 33554432  :  8,388,608   (2048x2048 bf16, shared LoRA folded)
//   pt      @ 41943040  :  4,194,304   (4x8192x64 bf16)
//   tb      @ 46137344  :  1,048,576   (8192x64 bf16)
//   caug    @ 47185920  :    262,144   (2048x64 bf16)
//   Ab      @ 47448064  :    393,216   (96x2048 bf16)
//   logits  @ 47841280  :        256   (4x8 f32, zeroed each launch)
// ---------------------------------------------------------------------------
extern "C" void kernel_launch(void* const* d_in, const int* in_sizes, int n_in,
                              void* d_out, int out_size, void* d_ws, size_t ws_size,
                              hipStream_t stream)
{
    const float* x        = (const float*)d_in[0];
    const float* base_W   = (const float*)d_in[1];
    const float* base_b   = (const float*)d_in[2];
    const float* shared_A = (const float*)d_in[3];
    const float* shared_B = (const float*)d_in[4];
    const float* expert_A = (const float*)d_in[5];
    const float* expert_B = (const float*)d_in[6];
    const float* task_emb = (const float*)d_in[7];
    const float* collab_w = (const float*)d_in[8];
    float* out = (float*)d_out;

    char* ws = (char*)d_ws;
    __bf16* xb     = (__bf16*)(ws + 0);
    __bf16* Wb     = (__bf16*)(ws + 33554432);
    __bf16* pt     = (__bf16*)(ws + 41943040);
    __bf16* tb     = (__bf16*)(ws + 46137344);
    __bf16* caug   = (__bf16*)(ws + 47185920);
    __bf16* Ab     = (__bf16*)(ws + 47448064);
    float*  logits = (float*) (ws + 47841280);

    hipMemsetAsync(logits, 0, 256, stream);
    prep_all    <<<dim3(12512), 256, 0, stream>>>(x, base_W, expert_A, shared_A,
                                                  expert_B, shared_B, task_emb, collab_w,
                                                  xb, Wb, caug, Ab);
    gemm_t      <<<dim3(256), 256, 0, stream>>>(xb, Ab, pt, logits);
    reduce_route<<<dim3(512), 256, 0, stream>>>(pt, logits, tb);
    gemm_main   <<<dim3(64, 16), 256, 0, stream>>>(xb, Wb, tb, caug, base_b, out);
}

// Round 8
// 235.194 us; speedup vs baseline: 1.0935x; 1.0008x over previous
//
#include <hip/hip_runtime.h>
#include <hip/hip_bf16.h>
#include <math.h>

// COLoRALinear: B=4, S=2048, D_IN=D_OUT=2048, E=8, R=8, SCALING=2.0
#define BATCH 4
#define SEQ   2048
#define DIN   2048
#define DOUT  2048
#define NEXP  8
#define RANK  8
#define MTOT  (BATCH * SEQ)   // 8192
#define KE    64              // expert aug rank (shared LoRA folded into Wb)
#define NKC   8               // split-K chunks in gemm_t

typedef __bf16 bf16x8 __attribute__((ext_vector_type(8)));
typedef __bf16 bf16x4 __attribute__((ext_vector_type(4)));
typedef float  f32x4  __attribute__((ext_vector_type(4)));

#define GLOBAL_AS __attribute__((address_space(1)))
#define LDS_AS    __attribute__((address_space(3)))

// ---------------------------------------------------------------------------
// K1 mega_prep (4736 blocks, heavy blocks first):
//  [0,512):     gemm_t tiles: kc = bid&7 (256-wide K chunk), mt = bid>>3.
//               Reads x fp32 directly, converts -> swizzled LDS (ds_write) AND
//               writes xb bf16 (each x element touched by exactly one tile).
//               B operand (rows 0-63 expert_A, 64-71 task_emb, 72-95 zero)
//               converted inline. Outputs pt[kc][m][64] and plog[bid][8]
//               (partial logits, full overwrite -> no memset needed).
//  [512,4608):  Wb = bf16(W + cw*2*shared_B@shared_A)
//  [4608,4736): caug[o][k] = (1-cw)*2*expert_B[k>>3][o][k&7]
// ---------------------------------------------------------------------------
__global__ __launch_bounds__(256) void mega_prep(
    const float* __restrict__ x, const float* __restrict__ W,
    const float* __restrict__ expert_A, const float* __restrict__ shared_A,
    const float* __restrict__ expert_B, const float* __restrict__ shared_B,
    const float* __restrict__ task_emb, const float* __restrict__ collab,
    __bf16* __restrict__ xb, __bf16* __restrict__ Wb,
    __bf16* __restrict__ caug, __bf16* __restrict__ pt, float* __restrict__ plog)
{
    const int bid = blockIdx.x;
    const int t = threadIdx.x;

    if (bid >= 512) {
        if (bid < 4608) {
            size_t idx = ((size_t)(bid - 512) * 256 + t) * 4;
            int o = (int)(idx >> 11), i = (int)(idx & 2047);
            float cw = 1.0f / (1.0f + expf(-collab[0]));
            float s = cw * 2.0f;
            float4 w = *(const float4*)&W[idx];
            float dx = 0.f, dy = 0.f, dz = 0.f, dw = 0.f;
            #pragma unroll
            for (int r = 0; r < 8; ++r) {
                float bs = shared_B[(size_t)o * RANK + r];
                float4 as = *(const float4*)&shared_A[(size_t)r * DIN + i];
                dx += bs * as.x; dy += bs * as.y; dz += bs * as.z; dw += bs * as.w;
            }
            bf16x4 h = { (__bf16)(w.x + s * dx), (__bf16)(w.y + s * dy),
                         (__bf16)(w.z + s * dz), (__bf16)(w.w + s * dw) };
            *(bf16x4*)&Wb[idx] = h;
        } else {
            int idx = ((bid - 4608) * 256 + t) * 4;   // over 2048*64
            int o = idx >> 6, k = idx & 63;           // k multiple of 4
            float cw = 1.0f / (1.0f + expf(-collab[0]));
            float s = (1.0f - cw) * 2.0f;
            float4 v = *(const float4*)&expert_B[((size_t)(k >> 3) * DOUT + o) * RANK + (k & 7)];
            bf16x4 h = { (__bf16)(s * v.x), (__bf16)(s * v.y),
                         (__bf16)(s * v.z), (__bf16)(s * v.w) };
            *(bf16x4*)&caug[idx] = h;
        }
        return;
    }

    // ---- gemm_t tile ----
    __shared__ __bf16 lsA[128 * 64];
    __shared__ __bf16 lsB[96 * 64];
    __shared__ float lsc[32];
    const int lane = t & 63;
    const int w = t >> 6;                 // wave: rows w*32 .. w*32+31
    const int kc = bid & 7;
    const int m0 = (bid >> 3) * 128;

    f32x4 acc[2][5];
    #pragma unroll
    for (int a = 0; a < 2; ++a)
        #pragma unroll
        for (int c = 0; c < 5; ++c) acc[a][c] = (f32x4){0.f, 0.f, 0.f, 0.f};

    for (int it = 0; it < 4; ++it) {
        int k0 = kc * 256 + it * 64;
        // A staging: x fp32 -> bf16 -> swizzled LDS + xb global store
        #pragma unroll
        for (int q = 0; q < 4; ++q) {
            int row = q * 32 + (t >> 3), sl = t & 7, seg = sl ^ (row & 7);
            const float* gp = x + (size_t)(m0 + row) * DIN + k0 + seg * 8;
            float4 v0 = *(const float4*)gp;
            float4 v1 = *(const float4*)(gp + 4);
            bf16x8 h = { (__bf16)v0.x, (__bf16)v0.y, (__bf16)v0.z, (__bf16)v0.w,
                         (__bf16)v1.x, (__bf16)v1.y, (__bf16)v1.z, (__bf16)v1.w };
            *(bf16x8*)&lsA[row * 64 + sl * 8] = h;
            *(bf16x8*)&xb[(size_t)(m0 + row) * DIN + k0 + seg * 8] = h;
        }
        // B staging: rows 0-63 expert_A, 64-71 task_emb, >=72 zero
        #pragma unroll
        for (int q = 0; q < 3; ++q) {
            int c = q * 256 + t;
            int row = c >> 3, sl = c & 7, seg = sl ^ (row & 7);
            bf16x8 h = { (__bf16)0.f, (__bf16)0.f, (__bf16)0.f, (__bf16)0.f,
                         (__bf16)0.f, (__bf16)0.f, (__bf16)0.f, (__bf16)0.f };
            if (row < 64) {
                const float* gp = expert_A + (size_t)row * DIN + k0 + seg * 8;
                float4 v0 = *(const float4*)gp, v1 = *(const float4*)(gp + 4);
                h = bf16x8{ (__bf16)v0.x, (__bf16)v0.y, (__bf16)v0.z, (__bf16)v0.w,
                            (__bf16)v1.x, (__bf16)v1.y, (__bf16)v1.z, (__bf16)v1.w };
            } else if (row < 72) {
                const float* gp = task_emb + (size_t)(row - 64) * DIN + k0 + seg * 8;
                float4 v0 = *(const float4*)gp, v1 = *(const float4*)(gp + 4);
                h = bf16x8{ (__bf16)v0.x, (__bf16)v0.y, (__bf16)v0.z, (__bf16)v0.w,
                            (__bf16)v1.x, (__bf16)v1.y, (__bf16)v1.z, (__bf16)v1.w };
            }
            *(bf16x8*)&lsB[row * 64 + sl * 8] = h;
        }
        __syncthreads();
        #pragma unroll
        for (int kk = 0; kk < 2; ++kk) {
            bf16x8 af[2], bfr[5];
            #pragma unroll
            for (int tm = 0; tm < 2; ++tm) {
                int r = w * 32 + tm * 16 + (lane & 15);
                int slot = (kk * 4 + (lane >> 4)) ^ (r & 7);
                af[tm] = *(const bf16x8*)&lsA[r * 64 + slot * 8];
            }
            #pragma unroll
            for (int tn = 0; tn < 5; ++tn) {
                int r = tn * 16 + (lane & 15);
                int slot = (kk * 4 + (lane >> 4)) ^ (r & 7);
                bfr[tn] = *(const bf16x8*)&lsB[r * 64 + slot * 8];
            }
            #pragma unroll
            for (int tm = 0; tm < 2; ++tm)
                #pragma unroll
                for (int tn = 0; tn < 5; ++tn)
                    acc[tm][tn] = __builtin_amdgcn_mfma_f32_16x16x32_bf16(
                        af[tm], bfr[tn], acc[tm][tn], 0, 0, 0);
        }
        __syncthreads();
    }

    // pt stores (cols 0-63)
    #pragma unroll
    for (int tm = 0; tm < 2; ++tm)
        #pragma unroll
        for (int tn = 0; tn < 4; ++tn) {
            int col = tn * 16 + (lane & 15);
            #pragma unroll
            for (int v = 0; v < 4; ++v) {
                int row = m0 + w * 32 + tm * 16 + (lane >> 4) * 4 + v;
                pt[((size_t)kc * MTOT + row) * KE + col] = (__bf16)acc[tm][tn][v];
            }
        }

    // partial logits (cols 64-71 live in frag tn=4, lanes with (lane&15)<8)
    float s = 0.f;
    #pragma unroll
    for (int tm = 0; tm < 2; ++tm)
        #pragma unroll
        for (int v = 0; v < 4; ++v) s += acc[tm][4][v];
    s += __shfl_down(s, 32);
    s += __shfl_down(s, 16);
    if (lane < 8) lsc[w * 8 + lane] = s;
    __syncthreads();
    if (t < 8)
        plog[bid * 8 + t] = lsc[t] + lsc[8 + t] + lsc[16 + t] + lsc[24 + t];
}

// ---------------------------------------------------------------------------
// K2 gemm_main: out = xb @ Wb^T + (softmax-scaled t) @ caug^T + bias
// Main: 32 BK=64 ksteps (R5/R7 structure verbatim: 8-slot XOR swizzle, hoisted
// addressing). Then (lsA/lsB free): reduce plog -> softmax f[8]; build the
// scaled tb tile in lsA (coalesced pt chunk loads, fp32 sum, *f[seg]) while
// caug DMAs into lsB; one correction kstep; fp32 epilogue with bias.
// grid (x=64 m-tiles, y=16 n-tiles) for XCD locality on the shared A-tile.
// ---------------------------------------------------------------------------
__global__ __launch_bounds__(256) void gemm_main(
    const __bf16* __restrict__ xb, const __bf16* __restrict__ Wb,
    const __bf16* __restrict__ pt, const __bf16* __restrict__ caug,
    const float* __restrict__ plog, const float* __restrict__ bias,
    float* __restrict__ out)
{
    __shared__ __bf16 lsA[128 * 64];
    __shared__ __bf16 lsB[128 * 64];
    __shared__ float scr[32 * 8];
    __shared__ float lgs[NEXP];
    const int t = threadIdx.x;
    const int lane = t & 63;
    const int wm = (t >> 6) >> 1, wn = (t >> 6) & 1;
    const int m0 = blockIdx.x * 128;
    const int n0 = blockIdx.y * 128;
    const int b  = m0 >> 11;

    int rowq[4], segq[4], ldso[4];
    #pragma unroll
    for (int q = 0; q < 4; ++q) {
        rowq[q] = q * 32 + (t >> 3);
        segq[q] = (t & 7) ^ (rowq[q] & 7);
        ldso[q] = (q * 256 + (t & ~63)) * 8;
    }
    const __bf16* pA[4]; const __bf16* pB[4];
    #pragma unroll
    for (int q = 0; q < 4; ++q) {
        pA[q] = xb + (size_t)(m0 + rowq[q]) * DIN + segq[q] * 8;
        pB[q] = Wb + (size_t)(n0 + rowq[q]) * DIN + segq[q] * 8;
    }
    int aoff[2][4], boff[2][4];
    #pragma unroll
    for (int tm = 0; tm < 4; ++tm) {
        int r = wm * 64 + tm * 16 + (lane & 15);
        #pragma unroll
        for (int kk = 0; kk < 2; ++kk)
            aoff[kk][tm] = r * 64 + (((kk * 4 + (lane >> 4)) ^ (r & 7)) * 8);
    }
    #pragma unroll
    for (int tn = 0; tn < 4; ++tn) {
        int r = wn * 64 + tn * 16 + (lane & 15);
        #pragma unroll
        for (int kk = 0; kk < 2; ++kk)
            boff[kk][tn] = r * 64 + (((kk * 4 + (lane >> 4)) ^ (r & 7)) * 8);
    }

    f32x4 acc[4][4];
    #pragma unroll
    for (int a = 0; a < 4; ++a)
        #pragma unroll
        for (int c = 0; c < 4; ++c) acc[a][c] = (f32x4){0.f, 0.f, 0.f, 0.f};

    // ---- main: K = 2048 over (xb, Wb), 32 iters of BK=64 ----
    for (int it = 0; it < 32; ++it) {
        #pragma unroll
        for (int q = 0; q < 4; ++q) {
            __builtin_amdgcn_global_load_lds((GLOBAL_AS void*)pA[q],
                (LDS_AS void*)&lsA[ldso[q]], 16, 0, 0);
            __builtin_amdgcn_global_load_lds((GLOBAL_AS void*)pB[q],
                (LDS_AS void*)&lsB[ldso[q]], 16, 0, 0);
            pA[q] += 64; pB[q] += 64;
        }
        __syncthreads();
        #pragma unroll
        for (int kk = 0; kk < 2; ++kk) {
            bf16x8 af[4], bfr[4];
            #pragma unroll
            for (int tm = 0; tm < 4; ++tm) af[tm]  = *(const bf16x8*)&lsA[aoff[kk][tm]];
            #pragma unroll
            for (int tn = 0; tn < 4; ++tn) bfr[tn] = *(const bf16x8*)&lsB[boff[kk][tn]];
            #pragma unroll
            for (int tm = 0; tm < 4; ++tm)
                #pragma unroll
                for (int tn = 0; tn < 4; ++tn)
                    acc[tm][tn] = __builtin_amdgcn_mfma_f32_16x16x32_bf16(
                        af[tm], bfr[tn], acc[tm][tn], 0, 0, 0);
        }
        __syncthreads();
    }

    // ---- correction phase ----
    // (a) caug -> lsB (DMA, drained by the barrier below)
    #pragma unroll
    for (int q = 0; q < 4; ++q) {
        const __bf16* qB = caug + (size_t)(n0 + rowq[q]) * KE + segq[q] * 8;
        __builtin_amdgcn_global_load_lds((GLOBAL_AS void*)qB,
            (LDS_AS void*)&lsB[ldso[q]], 16, 0, 0);
    }
    // (b) logits: sum plog[b*128 .. +128][8] -> softmax factors f[8]
    {
        const float* pb = plog + (size_t)b * 128 * 8;
        int e = t & 7, rr = t >> 3;          // rr 0..31
        float part = 0.f;
        #pragma unroll
        for (int j = 0; j < 4; ++j) part += pb[(rr + 32 * j) * 8 + e];
        scr[rr * 8 + e] = part;
    }
    __syncthreads();
    if (t < 8) {
        float s = 0.f;
        #pragma unroll
        for (int i = 0; i < 32; ++i) s += scr[i * 8 + t];
        lgs[t] = s;
    }
    __syncthreads();
    float f[NEXP];
    {
        float li[NEXP];
        #pragma unroll
        for (int e = 0; e < NEXP; ++e) li[e] = lgs[e] * (1.0f / (float)SEQ);
        float mx = li[0];
        #pragma unroll
        for (int e = 1; e < NEXP; ++e) mx = fmaxf(mx, li[e]);
        float den = 0.f;
        #pragma unroll
        for (int e = 0; e < NEXP; ++e) { f[e] = expf(li[e] - mx); den += f[e]; }
        float rden = 1.0f / den;
        #pragma unroll
        for (int e = 0; e < NEXP; ++e) f[e] *= rden;
    }
    // (c) build scaled tb tile into lsA (swizzled layout the readers expect)
    #pragma unroll
    for (int q = 0; q < 4; ++q) {
        int row = rowq[q], seg = segq[q];
        const __bf16* p0 = pt + (size_t)(m0 + row) * KE + seg * 8;
        float sum[8] = {0.f,0.f,0.f,0.f,0.f,0.f,0.f,0.f};
        #pragma unroll
        for (int kc = 0; kc < NKC; ++kc) {
            bf16x8 v = *(const bf16x8*)(p0 + (size_t)kc * MTOT * KE);
            #pragma unroll
            for (int j = 0; j < 8; ++j) sum[j] += (float)v[j];
        }
        float fe = f[seg];                    // chunk spans exactly one expert
        bf16x8 h;
        #pragma unroll
        for (int j = 0; j < 8; ++j) h[j] = (__bf16)(sum[j] * fe);
        *(bf16x8*)&lsA[row * 64 + (t & 7) * 8] = h;
    }
    __syncthreads();
    // (d) correction MFMAs (K=64)
    #pragma unroll
    for (int kk = 0; kk < 2; ++kk) {
        bf16x8 af[4], bfr[4];
        #pragma unroll
        for (int tm = 0; tm < 4; ++tm) af[tm]  = *(const bf16x8*)&lsA[aoff[kk][tm]];
        #pragma unroll
        for (int tn = 0; tn < 4; ++tn) bfr[tn] = *(const bf16x8*)&lsB[boff[kk][tn]];
        #pragma unroll
        for (int tm = 0; tm < 4; ++tm)
            #pragma unroll
            for (int tn = 0; tn < 4; ++tn)
                acc[tm][tn] = __builtin_amdgcn_mfma_f32_16x16x32_bf16(
                    af[tm], bfr[tn], acc[tm][tn], 0, 0, 0);
    }

    #pragma unroll
    for (int tm = 0; tm < 4; ++tm)
        #pragma unroll
        for (int tn = 0; tn < 4; ++tn) {
            int col = n0 + wn * 64 + tn * 16 + (lane & 15);
            float bv = bias[col];
            #pragma unroll
            for (int v = 0; v < 4; ++v) {
                int row = m0 + wm * 64 + tm * 16 + (lane >> 4) * 4 + v;
                out[(size_t)row * DOUT + col] = acc[tm][tn][v] + bv;
            }
        }
}

// ---------------------------------------------------------------------------
// Workspace (bytes):
//   xb   @ 0         : 33,554,432   (8192x2048 bf16)
//   Wb   @ 33554432  :  8,388,608   (2048x2048 bf16, shared LoRA folded)
//   pt   @ 41943040  :  8,388,608   (8x8192x64 bf16)
//   caug @ 50331648  :    262,144   (2048x64 bf16)
//   plog @ 50593792  :     16,384   (512x8 f32, fully overwritten)
// ---------------------------------------------------------------------------
extern "C" void kernel_launch(void* const* d_in, const int* in_sizes, int n_in,
                              void* d_out, int out_size, void* d_ws, size_t ws_size,
                              hipStream_t stream)
{
    const float* x        = (const float*)d_in[0];
    const float* base_W   = (const float*)d_in[1];
    const float* base_b   = (const float*)d_in[2];
    const float* shared_A = (const float*)d_in[3];
    const float* shared_B = (const float*)d_in[4];
    const float* expert_A = (const float*)d_in[5];
    const float* expert_B = (const float*)d_in[6];
    const float* task_emb = (const float*)d_in[7];
    const float* collab_w = (const float*)d_in[8];
    float* out = (float*)d_out;

    char* ws = (char*)d_ws;
    __bf16* xb   = (__bf16*)(ws + 0);
    __bf16* Wb   = (__bf16*)(ws + 33554432);
    __bf16* pt   = (__bf16*)(ws + 41943040);
    __bf16* caug = (__bf16*)(ws + 50331648);
    float*  plog = (float*) (ws + 50593792);

    mega_prep<<<dim3(4736), 256, 0, stream>>>(x, base_W, expert_A, shared_A,
                                              expert_B, shared_B, task_emb, collab_w,
                                              xb, Wb, caug, pt, plog);
    gemm_main<<<dim3(64, 16), 256, 0, stream>>>(xb, Wb, pt, caug, plog, base_b, out);
}